// Round 11
// baseline (44095.871 us; speedup 1.0000x reference)
//
#include <hip/hip_runtime.h>

#define T_SEQ 512
#define BB    128
#define HH    512
#define G4    2048
#define NBLK  256
#define NTHR  256
#define KC    64
#define NCHUNK 8
#define KP    32           // k-pairs per chunk
#define GTS   262144       // gtile slot size (floats) = 4mt*32row*4g*512

#define SCOPE __HIP_MEMORY_SCOPE_AGENT

typedef unsigned long long u64;
typedef unsigned u32;
typedef __fp16 half2v __attribute__((ext_vector_type(2)));

__device__ __forceinline__ float ldc(const float* p) {
    return __hip_atomic_load(p, __ATOMIC_RELAXED, SCOPE);
}
__device__ __forceinline__ void stc(float* p, float v) {
    __hip_atomic_store(p, v, __ATOMIC_RELAXED, SCOPE);
}
__device__ __forceinline__ u64 ldc64(const u64* p) {
    return __hip_atomic_load(p, __ATOMIC_RELAXED, SCOPE);
}
__device__ __forceinline__ void stc64(u64* p, u64 v) {
    __hip_atomic_store(p, v, __ATOMIC_RELAXED, SCOPE);
}
__device__ __forceinline__ u32 ldcu(const u32* p) {
    return __hip_atomic_load(p, __ATOMIC_RELAXED, SCOPE);
}
__device__ __forceinline__ void stcu(u32* p, u32 v) {
    __hip_atomic_store(p, v, __ATOMIC_RELAXED, SCOPE);
}
__device__ __forceinline__ u64 pack2(float a, float b) {
    union { float f[2]; u64 u; } x; x.f[0] = a; x.f[1] = b; return x.u;
}
__device__ __forceinline__ float2 unpack2(u64 v) {
    union { u64 u; float2 f; } x; x.u = v; return x.f;
}
__device__ __forceinline__ u32 pk2(float a, float b) {
    union { half2v h; u32 u; } t;
    t.h = __builtin_amdgcn_cvt_pkrtz(a, b);
    return t.u;
}
__device__ __forceinline__ float dot2(u32 a, u32 b, float c) {
    union { u32 u; half2v h; } x, y;
    x.u = a; y.u = b;
#if __has_builtin(__builtin_amdgcn_fdot2)
    return __builtin_amdgcn_fdot2(x.h, y.h, c, false);
#else
    return c + (float)x.h.x * (float)y.h.x + (float)x.h.y * (float)y.h.y;
#endif
}

// Per-mt-group joint barrier (64 blocks), flag-store arrival + ballot detect.
// Identical to the R6/R8/R10 proven mechanism.
__device__ __forceinline__ void gbar(u32* gf, u32 e, int wg, int tid) {
    asm volatile("s_waitcnt vmcnt(0)" ::: "memory");
    __syncthreads();
    if (tid == 0) stcu(gf + wg, e);
    if (tid < 64) {
        const u32* p = gf + tid;
        for (;;) {
            u32 v = ldcu(p);
            if (__all((int)(v - e) >= 0)) break;
            __builtin_amdgcn_s_sleep(1);
        }
    }
    __syncthreads();
    asm volatile("" ::: "memory");
}

#define DOT8(a, b, acc)                         \
    acc[0][0] = dot2(a.x, b.x, acc[0][0]);      \
    acc[0][1] = dot2(a.x, b.y, acc[0][1]);      \
    acc[0][2] = dot2(a.x, b.z, acc[0][2]);      \
    acc[0][3] = dot2(a.x, b.w, acc[0][3]);      \
    acc[1][0] = dot2(a.y, b.x, acc[1][0]);      \
    acc[1][1] = dot2(a.y, b.y, acc[1][1]);      \
    acc[1][2] = dot2(a.y, b.z, acc[1][2]);      \
    acc[1][3] = dot2(a.y, b.w, acc[1][3]);

// x-GEMM: A staged from Xin (plain fp32 -> packed f16), B = packed weights.
__device__ __forceinline__ void gemm_x(
    const float* __restrict__ Xin, int tt, const u32* __restrict__ Wp,
    float acc[2][4], u32 (*As2)[34], u32* Bs, int b0, int tid)
{
    const int xr  = tid >> 4;
    const int xc4 = tid & 15;
    const int ty  = tid >> 4;
    const int tx  = tid & 15;
    float4 vaX[2][2];
    uint4  vb16[2];

    auto loadA = [&](int c, int s) {
        #pragma unroll
        for (int it = 0; it < 2; ++it) {
            const float* p = Xin + ((size_t)(b0 + xr + 16*it) * T_SEQ + tt) * 512
                             + c * KC + 4 * xc4;
            vaX[s][it] = *(const float4*)p;
        }
    };
    auto loadB = [&](int c) {
        const uint4* p = (const uint4*)(Wp + (size_t)c * (KP * 64));
        vb16[0] = p[tid];
        vb16[1] = p[tid + 256];
    };
    auto writeLDS = [&](int s) {
        #pragma unroll
        for (int it = 0; it < 2; ++it) {
            const float4 v = vaX[s][it];
            As2[2*xc4+0][xr+16*it] = pk2(v.x, v.y);
            As2[2*xc4+1][xr+16*it] = pk2(v.z, v.w);
        }
        ((uint4*)Bs)[tid]       = vb16[0];
        ((uint4*)Bs)[tid + 256] = vb16[1];
    };

    loadA(0, 0);
    loadB(0);
    loadA(1, 1);
    for (int c = 0; c < NCHUNK; ++c) {
        __syncthreads();
        writeLDS(c & 1);
        __syncthreads();
        if (c + 2 < NCHUNK) loadA(c + 2, c & 1);
        if (c + 1 < NCHUNK) loadB(c + 1);
        #pragma unroll
        for (int kp = 0; kp < KP; ++kp) {
            uint2 a = *(const uint2*)&As2[kp][2 * ty];
            uint4 b = *(const uint4*)&Bs[kp * 64 + 4 * tx];
            DOT8(a, b, acc)
        }
    }
}

// h-GEMM: A read directly from the per-block LDS Abuf (written post-barrier
// by the previous step). Only B is staged per chunk.
__device__ __forceinline__ void gemm_h(
    const u32* __restrict__ Wp, float acc[2][4],
    const u32 (*Abuf)[34], u32* Bs, int tid)
{
    const int ty = tid >> 4;
    const int tx = tid & 15;
    uint4 vb16[2];
    auto loadB = [&](int c) {
        const uint4* p = (const uint4*)(Wp + (size_t)c * (KP * 64));
        vb16[0] = p[tid];
        vb16[1] = p[tid + 256];
    };
    loadB(0);
    for (int c = 0; c < NCHUNK; ++c) {
        __syncthreads();
        ((uint4*)Bs)[tid]       = vb16[0];
        ((uint4*)Bs)[tid + 256] = vb16[1];
        __syncthreads();
        if (c + 1 < NCHUNK) loadB(c + 1);
        #pragma unroll
        for (int kp = 0; kp < KP; ++kp) {
            uint2 a = *(const uint2*)&Abuf[c * KP + kp][2 * ty];
            uint4 b = *(const uint4*)&Bs[kp * 64 + 4 * tx];
            DOT8(a, b, acc)
        }
    }
}

// One layer, persistent cooperative kernel, ONE group barrier per step.
// Blocks 0..127   : x-blocks (mt,nt): gx(t+1) = Wih @ x_{t+1}, gx ping-pong.
// Blocks 128..255 : h-blocks (mt,nt): gh-GEMM + full gate tile write ->
//   barrier -> read group gate plane, local norms, duplicated c-state in regs,
//   h written directly into LDS Abuf as packed f16 (A-operand of next h-GEMM).
__global__ __launch_bounds__(NTHR)
void lstm_layer(const float* __restrict__ Xin,
                const u32* __restrict__ WpX,
                const u32* __restrict__ WpH,
                const float* __restrict__ bsum,
                const float* __restrict__ c0l,    // c0 + l*512, idx b*1024+j
                const float* __restrict__ h0l,    // h0 + l*512, idx b*1024+j
                float* __restrict__ gx,           // [2][BB*G4]   (sc1)
                float* __restrict__ gtile,        // [2][GTS]     (sc1)
                u32*   __restrict__ flags,        // [4][64]
                float* __restrict__ Out)          // [B][T][512] plain
{
    __shared__ u32 Abuf[256][34];   // full A: [kp 0..255][row 0..31]
    __shared__ u32 As2[KP][34];
    __shared__ u32 Bs[KP * 64];

    const int tid = threadIdx.x;
    const int bid = blockIdx.x;
    const bool isH = (bid >= 128);
    const int lb  = isH ? (bid - 128) : bid;
    const int mt  = lb >> 5;
    const int nt  = lb & 31;
    const int b0  = mt * 32;
    const int ty  = tid >> 4;
    const int tx  = tid & 15;
    const int jj  = nt * 16 + tx;

    u32* gf = flags + mt * 64;
    const int wg = (isH ? 32 : 0) + nt;
    u32 eb = 0;

    const u32* WpS = (isH ? WpH : WpX) + (size_t)nt * (256 * 64);

    float creg[2][32];   // duplicated c-state: rows 2ty,2ty+1 x cols 2(tx+16m)+e
    float bv[4] = {0.f, 0.f, 0.f, 0.f};

    if (isH) {
        #pragma unroll
        for (int g = 0; g < 4; ++g) bv[g] = bsum[g * 512 + jj];
        // seed c-state and Abuf (h(-1) = h0)
        #pragma unroll
        for (int r = 0; r < 2; ++r) {
            const int row = b0 + 2 * ty + r;
            #pragma unroll
            for (int m = 0; m < 16; ++m) {
                const int j0 = 2 * (tx + 16 * m);
                creg[r][2*m+0] = c0l[(size_t)row * 1024 + j0];
                creg[r][2*m+1] = c0l[(size_t)row * 1024 + j0 + 1];
                const float ha = h0l[(size_t)row * 1024 + j0];
                const float hb = h0l[(size_t)row * 1024 + j0 + 1];
                Abuf[tx + 16*m][2*ty + r] = pk2(ha, hb);
            }
        }
    } else {
        // prologue: gx(0) into slot 0
        float acc[2][4] = {};
        gemm_x(Xin, 0, WpS, acc, As2, Bs, b0, tid);
        #pragma unroll
        for (int r = 0; r < 2; ++r) {
            float* q = gx + (size_t)(b0 + 2*ty + r) * G4 + nt * 64 + 4 * tx;
            stc64((u64*)q,       pack2(acc[r][0], acc[r][1]));
            stc64((u64*)(q + 2), pack2(acc[r][2], acc[r][3]));
        }
    }
    ++eb; gbar(gf, eb, wg, tid);

    for (int t = 0; t < T_SEQ; ++t) {
        // ---------------- pre-barrier phase ----------------
        if (isH) {
            // prefetch gx(t) (hidden under GEMM)
            const float* gp = gx + (size_t)(t & 1) * (BB * G4);
            float gxv[2][4];
            #pragma unroll
            for (int r = 0; r < 2; ++r)
                #pragma unroll
                for (int g = 0; g < 4; ++g)
                    gxv[r][g] = ldc(gp + (size_t)(b0 + 2*ty + r) * G4 + g * 512 + jj);

            float acc[2][4] = {};
            gemm_h(WpS, acc, Abuf, Bs, tid);

            // write complete gate tile (gh + gx + bias), coalesced layout
            float* gt = gtile + (size_t)(t & 1) * GTS;
            #pragma unroll
            for (int r = 0; r < 2; ++r) {
                const size_t rb = (size_t)(mt * 32 + 2*ty + r) * 4;
                #pragma unroll
                for (int g = 0; g < 4; ++g)
                    stc(gt + (rb + g) * 512 + jj, acc[r][g] + gxv[r][g] + bv[g]);
            }
        } else if (t + 1 < T_SEQ) {
            float acc[2][4] = {};
            gemm_x(Xin, t + 1, WpS, acc, As2, Bs, b0, tid);
            float* gp = gx + (size_t)((t + 1) & 1) * (BB * G4);
            #pragma unroll
            for (int r = 0; r < 2; ++r) {
                float* q = gp + (size_t)(b0 + 2*ty + r) * G4 + nt * 64 + 4 * tx;
                stc64((u64*)q,       pack2(acc[r][0], acc[r][1]));
                stc64((u64*)(q + 2), pack2(acc[r][2], acc[r][3]));
            }
        }
        ++eb; gbar(gf, eb, wg, tid);   // the ONLY barrier per step

        // ---------------- post-barrier phase (h-blocks) ----------------
        if (isH) {
            const float* gt = gtile + (size_t)(t & 1) * GTS;

            // pass 1: row L1 norms over owned cols, then 16-lane butterfly
            float sn[2][3] = {{0.f,0.f,0.f},{0.f,0.f,0.f}};
            #pragma unroll
            for (int r = 0; r < 2; ++r) {
                const size_t rb = (size_t)(mt * 32 + 2*ty + r) * 4;
                #pragma unroll
                for (int m = 0; m < 16; ++m) {
                    const int j = 2 * (tx + 16 * m);
                    float2 vi = unpack2(ldc64((const u64*)(gt + (rb+0)*512 + j)));
                    float2 vf = unpack2(ldc64((const u64*)(gt + (rb+1)*512 + j)));
                    float2 vo = unpack2(ldc64((const u64*)(gt + (rb+3)*512 + j)));
                    sn[r][0] += fabsf(vi.x) + fabsf(vi.y);
                    sn[r][1] += fabsf(vf.x) + fabsf(vf.y);
                    sn[r][2] += fabsf(vo.x) + fabsf(vo.y);
                }
            }
            #pragma unroll
            for (int d = 1; d < 16; d <<= 1) {
                #pragma unroll
                for (int r = 0; r < 2; ++r) {
                    sn[r][0] += __shfl_xor(sn[r][0], d, 16);
                    sn[r][1] += __shfl_xor(sn[r][1], d, 16);
                    sn[r][2] += __shfl_xor(sn[r][2], d, 16);
                }
            }
            float inv[2][3];
            #pragma unroll
            for (int r = 0; r < 2; ++r)
                #pragma unroll
                for (int g = 0; g < 3; ++g)
                    inv[r][g] = 1.f / fmaxf(sn[r][g], 1e-12f);

            // pass 2: gate nonlinearity + c update + h -> LDS Abuf (+ Out slice)
            #pragma unroll
            for (int r = 0; r < 2; ++r) {
                const size_t rb = (size_t)(mt * 32 + 2*ty + r) * 4;
                const int row = b0 + 2*ty + r;
                #pragma unroll
                for (int m = 0; m < 16; ++m) {
                    const int kp = tx + 16 * m;
                    const int j  = 2 * kp;
                    float2 vi = unpack2(ldc64((const u64*)(gt + (rb+0)*512 + j)));
                    float2 vf = unpack2(ldc64((const u64*)(gt + (rb+1)*512 + j)));
                    float2 vc = unpack2(ldc64((const u64*)(gt + (rb+2)*512 + j)));
                    float2 vo = unpack2(ldc64((const u64*)(gt + (rb+3)*512 + j)));
                    float h2[2];
                    #pragma unroll
                    for (int e = 0; e < 2; ++e) {
                        const float gi = e ? vi.y : vi.x;
                        const float gf2 = e ? vf.y : vf.x;
                        const float gc = e ? vc.y : vc.x;
                        const float go = e ? vo.y : vo.x;
                        const float iv = 1.f / (1.f + expf(-gi * inv[r][0]));
                        const float fv = 1.f / (1.f + expf(-gf2 * inv[r][1]));
                        const float ov = 1.f / (1.f + expf(-go * inv[r][2]));
                        const float cn = fv * creg[r][2*m+e] + iv * gc;
                        creg[r][2*m+e] = cn;
                        h2[e] = ov * fmaxf(cn, 0.f);
                    }
                    Abuf[kp][2*ty + r] = pk2(h2[0], h2[1]);
                    if (m == (nt >> 1) && (tx >> 3) == (nt & 1)) {
                        *(float2*)&Out[((size_t)row * T_SEQ + t) * 512 + j] =
                            make_float2(h2[0], h2[1]);
                    }
                }
            }
        }
        // no second barrier: Abuf is block-private; gtile/gx are ping-ponged
        // and their WAR is ordered by the next step's barrier.
    }
}

// Pack weights to f16 k-pairs (unchanged from R10):
//   Wp_u32[l][nt][kp][c] = pack_f16( W[row(c)][2kp], W[row(c)][2kp+1] )
//   row(c) = nt*64+c (Wih) or (c&3)*512 + nt*16 + (c>>2) (Whh)
__global__ __launch_bounds__(256)
void pack_w(const float* __restrict__ Wih, const float* __restrict__ Whh,
            const float* __restrict__ bih, const float* __restrict__ bhh,
            u32* __restrict__ WpX, u32* __restrict__ WpH, float* __restrict__ bsum)
{
    __shared__ float tile[64][65];
    const int tid = threadIdx.x;
    const int blk = blockIdx.x;
    if (blk < 16) bsum[blk * 256 + tid] = bih[blk * 256 + tid] + bhh[blk * 256 + tid];

    const int mat = blk & 1;
    const int kc  = (blk >> 1) & 7;
    const int nt  = (blk >> 4) & 31;
    const int l   = blk >> 9;
    const float* W = mat ? Whh : Wih;
    u32* Wp = mat ? WpH : WpX;

    const int c  = tid >> 2;
    const int ko = (tid & 3) * 16;
    const int grow = mat ? ((c & 3) * 512 + nt * 16 + (c >> 2))
                         : (nt * 64 + c);
    const float* src = W + ((size_t)(l * G4 + grow)) * 512 + kc * 64 + ko;
    #pragma unroll
    for (int it = 0; it < 4; ++it) {
        float4 v = ((const float4*)src)[it];
        tile[c][ko + 4*it + 0] = v.x;
        tile[c][ko + 4*it + 1] = v.y;
        tile[c][ko + 4*it + 2] = v.z;
        tile[c][ko + 4*it + 3] = v.w;
    }
    __syncthreads();
    const int kp = tid >> 3;
    const int cb = (tid & 7) * 8;
    u32* dst = Wp + ((size_t)((l * 32 + nt) * 256) + kc * 32 + kp) * 64 + cb;
    #pragma unroll
    for (int j = 0; j < 8; ++j)
        dst[j] = pk2(tile[cb + j][2 * kp], tile[cb + j][2 * kp + 1]);
}

__global__ __launch_bounds__(256)
void init_layer(u32* __restrict__ flags)
{
    const int idx = blockIdx.x * blockDim.x + threadIdx.x;
    if (idx < 1024) flags[idx] = 0u;
}

extern "C" void kernel_launch(void* const* d_in, const int* in_sizes, int n_in,
                              void* d_out, int out_size, void* d_ws, size_t ws_size,
                              hipStream_t stream)
{
    const float* x   = (const float*)d_in[0];
    const float* h0  = (const float*)d_in[1];
    const float* c0  = (const float*)d_in[2];
    const float* Wih = (const float*)d_in[3];
    const float* bih = (const float*)d_in[4];
    const float* Whh = (const float*)d_in[5];
    const float* bhh = (const float*)d_in[6];
    float* out = (float*)d_out;
    float* ws  = (float*)d_ws;

    // ws layout (floats), total ~8.1 MB
    u32*   flags = (u32*)ws;                    // 1024 u32
    float* gx    = ws + 1024;                   // 2*262144 = 524288
    float* gtile = gx + 2 * (BB * G4);          // 2*262144 = 524288
    u32*   WpX   = (u32*)(gtile + 2 * GTS);     // 2 layers * 524288 u32
    u32*   WpH   = WpX + 2 * 524288;            // 2 layers * 524288 u32
    float* bsum  = (float*)(WpH + 2 * 524288);  // 4096

    hipLaunchKernelGGL(pack_w, dim3(1024), dim3(256), 0, stream,
                       Wih, Whh, bih, bhh, WpX, WpH, bsum);

    for (int l = 0; l < 2; ++l) {
        hipLaunchKernelGGL(init_layer, dim3(4), dim3(256), 0, stream, flags);
        const float* Xin  = (l == 0) ? x : (const float*)out;
        const u32*   WpXl = WpX + (size_t)l * 524288;
        const u32*   WpHl = WpH + (size_t)l * 524288;
        const float* bsl  = bsum + l * 2048;
        const float* c0l  = c0 + l * 512;
        const float* h0l  = h0 + l * 512;
        void* args[] = {(void*)&Xin, (void*)&WpXl, (void*)&WpHl, (void*)&bsl,
                        (void*)&c0l, (void*)&h0l,
                        (void*)&gx, (void*)&gtile, (void*)&flags, (void*)&out};
        hipLaunchCooperativeKernel(reinterpret_cast<void*>(lstm_layer),
                                   dim3(NBLK), dim3(NTHR), args, 0, stream);
    }
}

// Round 14
// 31334.210 us; speedup vs baseline: 1.4073x; 1.4073x over previous
//
#include <hip/hip_runtime.h>

#define T_SEQ 512
#define BB    128
#define HH    512
#define G4    2048
#define KH    512
#define NTHR  256
#define KC    64
#define NCHUNK (KH / KC)   // 8
#define KP    32           // k-pairs per chunk

#define SCOPE __HIP_MEMORY_SCOPE_AGENT

typedef unsigned long long u64;
typedef unsigned u32;
typedef unsigned short u16;
typedef __fp16 half2v __attribute__((ext_vector_type(2)));

__device__ __forceinline__ float ldc(const float* p) {
    return __hip_atomic_load(p, __ATOMIC_RELAXED, SCOPE);
}
__device__ __forceinline__ void stc(float* p, float v) {
    __hip_atomic_store(p, v, __ATOMIC_RELAXED, SCOPE);
}
__device__ __forceinline__ u64 ldc64(const u64* p) {
    return __hip_atomic_load(p, __ATOMIC_RELAXED, SCOPE);
}
__device__ __forceinline__ void stc64(u64* p, u64 v) {
    __hip_atomic_store(p, v, __ATOMIC_RELAXED, SCOPE);
}
__device__ __forceinline__ u32 ldcu(const u32* p) {
    return __hip_atomic_load(p, __ATOMIC_RELAXED, SCOPE);
}
__device__ __forceinline__ void stcu(u32* p, u32 v) {
    __hip_atomic_store(p, v, __ATOMIC_RELAXED, SCOPE);
}
__device__ __forceinline__ u64 pack2(float a, float b) {
    union { float f[2]; u64 u; } x; x.f[0] = a; x.f[1] = b; return x.u;
}
__device__ __forceinline__ float2 unpack2(u64 v) {
    union { u64 u; float2 f; } x; x.u = v; return x.f;
}
__device__ __forceinline__ u32 pk2(float a, float b) {
    union { half2v h; u32 u; } t;
    t.h = __builtin_amdgcn_cvt_pkrtz(a, b);
    return t.u;
}
__device__ __forceinline__ float dot2(u32 a, u32 b, float c) {
    union { u32 u; half2v h; } x, y;
    x.u = a; y.u = b;
#if __has_builtin(__builtin_amdgcn_fdot2)
    return __builtin_amdgcn_fdot2(x.h, y.h, c, false);
#else
    return c + (float)x.h.x * (float)y.h.x + (float)x.h.y * (float)y.h.y;
#endif
}
__device__ __forceinline__ u16 f2h(float v) {
    union { __fp16 h; u16 u; } cv; cv.h = (__fp16)v; return cv.u;
}
__device__ __forceinline__ float h2f(u16 v) {
    union { u16 u; __fp16 h; } cv; cv.u = v; return (float)cv.h;
}

// 64-flag joint barrier (R10 verbatim).
__device__ __forceinline__ void gbar(u32* gf, u32 e, int wg, int tid) {
    asm volatile("s_waitcnt vmcnt(0)" ::: "memory");
    __syncthreads();
    if (tid == 0) stcu(gf + wg, e);
    if (tid < 64) {
        const u32* p = gf + tid;
        for (;;) {
            u32 v = ldcu(p);
            if (__all((int)(v - e) >= 0)) break;
            __builtin_amdgcn_s_sleep(1);
        }
    }
    __syncthreads();
    asm volatile("" ::: "memory");
}
// 32-flag variant: lanes 0..31 and 32..63 poll the same 32 flags.
__device__ __forceinline__ void gbar32(u32* gf, u32 e, int wg, int tid) {
    asm volatile("s_waitcnt vmcnt(0)" ::: "memory");
    __syncthreads();
    if (tid == 0) stcu(gf + wg, e);
    if (tid < 64) {
        const u32* p = gf + (tid & 31);
        for (;;) {
            u32 v = ldcu(p);
            if (__all((int)(v - e) >= 0)) break;
            __builtin_amdgcn_s_sleep(1);
        }
    }
    __syncthreads();
    asm volatile("" ::: "memory");
}

// R10-verbatim tiled GEMM for one 32x64 tile, K=512.
template<bool XPATH>
__device__ __forceinline__ void gemm_tile(
    const float* __restrict__ Asrc, int tt,
    const u32* __restrict__ Wp,
    float acc[2][4],
    u32 (*As2)[34], u32* Bs,
    int b0, int tid)
{
    const int sr8 = tid >> 5;
    const int sc2 = tid & 31;
    const int xr  = tid >> 4;
    const int xc4 = tid & 15;
    const int ty  = tid >> 4;
    const int tx  = tid & 15;

    u64   vaH[2][4];
    float4 vaX[2][2];
    uint4  vb16[2];

    auto loadA = [&](int c, int s) {
        if (XPATH) {
            #pragma unroll
            for (int it = 0; it < 2; ++it) {
                const float* p = Asrc + ((size_t)(b0 + xr + 16*it) * T_SEQ + tt) * 512
                                 + c * KC + 4 * xc4;
                vaX[s][it] = *(const float4*)p;
            }
        } else {
            #pragma unroll
            for (int it = 0; it < 4; ++it) {
                const float* p = Asrc + (size_t)(b0 + sr8 + 8*it) * 512 + c * KC + 2 * sc2;
                vaH[s][it] = ldc64((const u64*)p);
            }
        }
    };
    auto loadB = [&](int c) {
        const uint4* p = (const uint4*)(Wp + (size_t)c * (KP * 64));
        vb16[0] = p[tid];
        vb16[1] = p[tid + 256];
    };
    auto writeLDS = [&](int s) {
        if (XPATH) {
            #pragma unroll
            for (int it = 0; it < 2; ++it) {
                const float4 v = vaX[s][it];
                As2[2*xc4+0][xr+16*it] = pk2(v.x, v.y);
                As2[2*xc4+1][xr+16*it] = pk2(v.z, v.w);
            }
        } else {
            #pragma unroll
            for (int it = 0; it < 4; ++it) {
                float2 f = unpack2(vaH[s][it]);
                As2[sc2][sr8+8*it] = pk2(f.x, f.y);
            }
        }
        ((uint4*)Bs)[tid]       = vb16[0];
        ((uint4*)Bs)[tid + 256] = vb16[1];
    };

    loadA(0, 0);
    loadB(0);
    loadA(1, 1);
    for (int c = 0; c < NCHUNK; ++c) {
        __syncthreads();
        writeLDS(c & 1);
        __syncthreads();
        if (c + 2 < NCHUNK) loadA(c + 2, c & 1);
        if (c + 1 < NCHUNK) loadB(c + 1);
        #pragma unroll
        for (int kp = 0; kp < KP; ++kp) {
            uint2 a = *(const uint2*)&As2[kp][2 * ty];
            uint4 b = *(const uint4*)&Bs[kp * 64 + 4 * tx];
            acc[0][0] = dot2(a.x, b.x, acc[0][0]);
            acc[0][1] = dot2(a.x, b.y, acc[0][1]);
            acc[0][2] = dot2(a.x, b.z, acc[0][2]);
            acc[0][3] = dot2(a.x, b.w, acc[0][3]);
            acc[1][0] = dot2(a.y, b.x, acc[1][0]);
            acc[1][1] = dot2(a.y, b.y, acc[1][1]);
            acc[1][2] = dot2(a.y, b.z, acc[1][2]);
            acc[1][3] = dot2(a.y, b.w, acc[1][3]);
        }
    }
}

// ===== Prepass: gxbuf[t][b][2048] f16 = Xin[b][t] @ Wih^T (raw cols) =========
__global__ __launch_bounds__(NTHR)
void prepass_gx(const float* __restrict__ Xin,
                const u32* __restrict__ WpXl,
                u16* __restrict__ gxbuf)
{
    __shared__ u32 As2[KP][34];
    __shared__ u32 Bs[KP * 64];
    const int tid = threadIdx.x;
    const int blk = blockIdx.x;
    const int nt = blk & 31;
    const int tg = (blk >> 5) & 15;
    const int b  = blk >> 9;
    const int t0 = tg * 32;
    const int xr = tid >> 4, xc4 = tid & 15;
    const int ty = tid >> 4, tx = tid & 15;
    const u32* Wp = WpXl + (size_t)nt * (256 * 64);
    const float* Ab = Xin + ((size_t)b * T_SEQ + t0) * 512;

    float4 vaX[2][2];
    uint4  vb16[2];
    float acc[2][4] = {};

    auto loadA = [&](int c, int s) {
        #pragma unroll
        for (int it = 0; it < 2; ++it)
            vaX[s][it] = *(const float4*)(Ab + (size_t)(xr + 16*it) * 512 + c * KC + 4 * xc4);
    };
    auto loadB = [&](int c) {
        const uint4* q = (const uint4*)(Wp + (size_t)c * (KP * 64));
        vb16[0] = q[tid];
        vb16[1] = q[tid + 256];
    };

    loadA(0, 0);
    loadB(0);
    loadA(1, 1);
    for (int c = 0; c < NCHUNK; ++c) {
        __syncthreads();
        #pragma unroll
        for (int it = 0; it < 2; ++it) {
            const float4 v = vaX[c & 1][it];
            As2[2*xc4+0][xr+16*it] = pk2(v.x, v.y);
            As2[2*xc4+1][xr+16*it] = pk2(v.z, v.w);
        }
        ((uint4*)Bs)[tid]       = vb16[0];
        ((uint4*)Bs)[tid + 256] = vb16[1];
        __syncthreads();
        if (c + 2 < NCHUNK) loadA(c + 2, c & 1);
        if (c + 1 < NCHUNK) loadB(c + 1);
        #pragma unroll
        for (int kp = 0; kp < KP; ++kp) {
            uint2 a = *(const uint2*)&As2[kp][2 * ty];
            uint4 bq = *(const uint4*)&Bs[kp * 64 + 4 * tx];
            acc[0][0] = dot2(a.x, bq.x, acc[0][0]);
            acc[0][1] = dot2(a.x, bq.y, acc[0][1]);
            acc[0][2] = dot2(a.x, bq.z, acc[0][2]);
            acc[0][3] = dot2(a.x, bq.w, acc[0][3]);
            acc[1][0] = dot2(a.y, bq.x, acc[1][0]);
            acc[1][1] = dot2(a.y, bq.y, acc[1][1]);
            acc[1][2] = dot2(a.y, bq.z, acc[1][2]);
            acc[1][3] = dot2(a.y, bq.w, acc[1][3]);
        }
    }
    #pragma unroll
    for (int r = 0; r < 2; ++r) {
        const int t = t0 + 2 * ty + r;
        const u64 w = (u64)f2h(acc[r][0])
                    | ((u64)f2h(acc[r][1]) << 16)
                    | ((u64)f2h(acc[r][2]) << 32)
                    | ((u64)f2h(acc[r][3]) << 48);
        *(u64*)(gxbuf + ((size_t)t * BB + b) * G4 + nt * 64 + 4 * tx) = w;
    }
}

// ===== Fast recurrence: 128 h-blocks (4 groups x 32), gx from gxbuf =========
__global__ __launch_bounds__(NTHR)
void lstm_h(const u16* __restrict__ gxbuf,
            const u32* __restrict__ WpHl,
            const float* __restrict__ bsum,
            const float* __restrict__ c0l,
            float* __restrict__ hbuf,          // [128*512] fp32 (sc1)
            float* __restrict__ part,          // [4][32][32][4]  (sc1)
            u32*   __restrict__ flags,         // [4][64]
            float* __restrict__ Out)
{
    __shared__ u32 As2[KP][34];
    __shared__ u32 Bs[KP * 64];

    const int tid = threadIdx.x;
    const int bid = blockIdx.x;
    const int mt  = bid >> 5;
    const int nt  = bid & 31;
    const int b0  = mt * 32;
    const int ty  = tid >> 4;
    const int tx  = tid & 15;
    const int r0  = b0 + 2 * ty;
    const int jj  = nt * 16 + tx;

    u32* gf = flags + mt * 64;
    u32 eb = 0;

    const u32* Wp = WpHl + (size_t)nt * (256 * 64);   // FIXED: was KH*64 (OOB for nt>=16)

    float creg[2], bv[4];
    creg[0] = c0l[(size_t)(r0 + 0) * 1024 + jj];
    creg[1] = c0l[(size_t)(r0 + 1) * 1024 + jj];
    #pragma unroll
    for (int g = 0; g < 4; ++g) bv[g] = bsum[g * 512 + jj];

    ++eb; gbar32(gf, eb, nt, tid);

    for (int t = 0; t < T_SEQ; ++t) {
        float gv[2][4];

        // ---------------- Phase A ----------------
        const u16* gp = gxbuf + (size_t)t * (BB * G4);
        float gxv[2][4];
        #pragma unroll
        for (int r = 0; r < 2; ++r)
            #pragma unroll
            for (int g = 0; g < 4; ++g)
                gxv[r][g] = h2f(gp[(size_t)(r0 + r) * G4 + g * 512 + jj]);

        float acc[2][4] = {};
        gemm_tile<false>(hbuf, 0, Wp, acc, As2, Bs, b0, tid);

        float sa[2][3];
        #pragma unroll
        for (int r = 0; r < 2; ++r) {
            #pragma unroll
            for (int g = 0; g < 4; ++g) gv[r][g] = acc[r][g] + gxv[r][g] + bv[g];
            sa[r][0] = fabsf(gv[r][0]);
            sa[r][1] = fabsf(gv[r][1]);
            sa[r][2] = fabsf(gv[r][3]);
        }
        #pragma unroll
        for (int d = 1; d < 16; d <<= 1) {
            #pragma unroll
            for (int r = 0; r < 2; ++r) {
                sa[r][0] += __shfl_xor(sa[r][0], d, 16);
                sa[r][1] += __shfl_xor(sa[r][1], d, 16);
                sa[r][2] += __shfl_xor(sa[r][2], d, 16);
            }
        }
        if (tx == 0) {
            float* pw = part + (size_t)((mt * 32 + nt) * 32) * 4;
            #pragma unroll
            for (int r = 0; r < 2; ++r) {
                const int row = 2 * ty + r;
                stc(pw + row * 4 + 0, sa[r][0]);
                stc(pw + row * 4 + 1, sa[r][1]);
                stc(pw + row * 4 + 2, sa[r][2]);
            }
        }
        ++eb; gbar32(gf, eb, nt, tid);

        // ---------------- Phase B ----------------
        float s[2][3];
        {
            const float* pb = part + (size_t)(mt * 32) * 32 * 4;
            #pragma unroll
            for (int r = 0; r < 2; ++r) {
                const int row = 2 * ty + r;
                #pragma unroll
                for (int g = 0; g < 3; ++g)
                    s[r][g] = ldc(pb + ((size_t)tx * 32 + row) * 4 + g)
                            + ldc(pb + ((size_t)(tx + 16) * 32 + row) * 4 + g);
            }
        }
        #pragma unroll
        for (int d = 1; d < 16; d <<= 1) {
            #pragma unroll
            for (int r = 0; r < 2; ++r) {
                s[r][0] += __shfl_xor(s[r][0], d, 16);
                s[r][1] += __shfl_xor(s[r][1], d, 16);
                s[r][2] += __shfl_xor(s[r][2], d, 16);
            }
        }
        #pragma unroll
        for (int r = 0; r < 2; ++r) {
            const int b = r0 + r;
            const float iv = 1.f / (1.f + expf(-gv[r][0] / fmaxf(s[r][0], 1e-12f)));
            const float fv = 1.f / (1.f + expf(-gv[r][1] / fmaxf(s[r][1], 1e-12f)));
            const float ov = 1.f / (1.f + expf(-gv[r][3] / fmaxf(s[r][2], 1e-12f)));
            const float cn = fv * creg[r] + iv * gv[r][2];
            creg[r] = cn;
            const float hn = ov * fmaxf(cn, 0.f);
            stc(hbuf + (size_t)b * 512 + jj, hn);
            Out[((size_t)b * T_SEQ + t) * 512 + jj] = hn;
        }
        ++eb; gbar32(gf, eb, nt, tid);
    }
}

// ===== Fallback: R10 lstm_layer VERBATIM ====================================
__global__ __launch_bounds__(NTHR)
void lstm_layer(const float* __restrict__ Xin,
                const u32* __restrict__ WpX,
                const u32* __restrict__ WpH,
                const float* __restrict__ bsum,
                const float* __restrict__ c0l,
                float* __restrict__ hbuf,
                float* __restrict__ gx,
                float* __restrict__ part,
                u32*   __restrict__ flags,
                float* __restrict__ Out)
{
    __shared__ u32 As2[KP][34];
    __shared__ u32 Bs[KP * 64];

    const int tid = threadIdx.x;
    const int bid = blockIdx.x;
    const bool isH = (bid >= 128);
    const int lb  = isH ? (bid - 128) : bid;
    const int mt  = lb >> 5;
    const int nt  = lb & 31;
    const int b0  = mt * 32;
    const int ty  = tid >> 4;
    const int tx  = tid & 15;
    const int r0  = b0 + 2 * ty;
    const int jj  = nt * 16 + tx;

    u32* gf = flags + mt * 64;
    const int wg = (isH ? 32 : 0) + nt;
    u32 eb = 0;

    const u32* Wp = (isH ? WpH : WpX) + (size_t)nt * (256 * 64);

    float creg[2] = {0.f, 0.f}, bv[4] = {0.f, 0.f, 0.f, 0.f};
    if (isH) {
        creg[0] = c0l[(size_t)(r0 + 0) * 1024 + jj];
        creg[1] = c0l[(size_t)(r0 + 1) * 1024 + jj];
        #pragma unroll
        for (int g = 0; g < 4; ++g) bv[g] = bsum[g * 512 + jj];
    }

    if (!isH) {
        float acc[2][4] = {};
        gemm_tile<true>(Xin, 0, Wp, acc, As2, Bs, b0, tid);
        #pragma unroll
        for (int r = 0; r < 2; ++r) {
            float* q = gx + (size_t)(r0 + r) * G4 + nt * 64 + 4 * tx;
            stc64((u64*)q,       pack2(acc[r][0], acc[r][1]));
            stc64((u64*)(q + 2), pack2(acc[r][2], acc[r][3]));
        }
    }
    ++eb; gbar(gf, eb, wg, tid);

    for (int t = 0; t < T_SEQ; ++t) {
        const int p = t & 1;
        float gv[2][4];

        if (isH) {
            float acc[2][4] = {};
            gemm_tile<false>(hbuf, 0, Wp, acc, As2, Bs, b0, tid);
            const float* gp = gx + (size_t)p * (BB * G4);
            float sa[2][3];
            #pragma unroll
            for (int r = 0; r < 2; ++r) {
                const int b = r0 + r;
                #pragma unroll
                for (int g = 0; g < 4; ++g) {
                    const int col = g * 512 + jj;
                    gv[r][g] = acc[r][g] + ldc(gp + (size_t)b * G4 + col) + bv[g];
                }
                sa[r][0] = fabsf(gv[r][0]);
                sa[r][1] = fabsf(gv[r][1]);
                sa[r][2] = fabsf(gv[r][3]);
            }
            #pragma unroll
            for (int d = 1; d < 16; d <<= 1) {
                #pragma unroll
                for (int r = 0; r < 2; ++r) {
                    sa[r][0] += __shfl_xor(sa[r][0], d, 16);
                    sa[r][1] += __shfl_xor(sa[r][1], d, 16);
                    sa[r][2] += __shfl_xor(sa[r][2], d, 16);
                }
            }
            if (tx == 0) {
                float* pw = part + (size_t)((mt * 32 + nt) * 32) * 4;
                #pragma unroll
                for (int r = 0; r < 2; ++r) {
                    const int row = 2 * ty + r;
                    stc(pw + row * 4 + 0, sa[r][0]);
                    stc(pw + row * 4 + 1, sa[r][1]);
                    stc(pw + row * 4 + 2, sa[r][2]);
                }
            }
        } else if (t + 1 < T_SEQ) {
            float acc[2][4] = {};
            gemm_tile<true>(Xin, t + 1, Wp, acc, As2, Bs, b0, tid);
            float* gp = gx + (size_t)((t + 1) & 1) * (BB * G4);
            #pragma unroll
            for (int r = 0; r < 2; ++r) {
                float* q = gp + (size_t)(r0 + r) * G4 + nt * 64 + 4 * tx;
                stc64((u64*)q,       pack2(acc[r][0], acc[r][1]));
                stc64((u64*)(q + 2), pack2(acc[r][2], acc[r][3]));
            }
        }
        ++eb; gbar(gf, eb, wg, tid);

        if (isH) {
            float s[2][3];
            {
                const float* pb = part + (size_t)(mt * 32) * 32 * 4;
                #pragma unroll
                for (int r = 0; r < 2; ++r) {
                    const int row = 2 * ty + r;
                    #pragma unroll
                    for (int g = 0; g < 3; ++g)
                        s[r][g] = ldc(pb + ((size_t)tx * 32 + row) * 4 + g)
                                + ldc(pb + ((size_t)(tx + 16) * 32 + row) * 4 + g);
                }
            }
            #pragma unroll
            for (int d = 1; d < 16; d <<= 1) {
                #pragma unroll
                for (int r = 0; r < 2; ++r) {
                    s[r][0] += __shfl_xor(s[r][0], d, 16);
                    s[r][1] += __shfl_xor(s[r][1], d, 16);
                    s[r][2] += __shfl_xor(s[r][2], d, 16);
                }
            }
            #pragma unroll
            for (int r = 0; r < 2; ++r) {
                const int b = r0 + r;
                const float iv = 1.f / (1.f + expf(-gv[r][0] / fmaxf(s[r][0], 1e-12f)));
                const float fv = 1.f / (1.f + expf(-gv[r][1] / fmaxf(s[r][1], 1e-12f)));
                const float ov = 1.f / (1.f + expf(-gv[r][3] / fmaxf(s[r][2], 1e-12f)));
                const float cn = fv * creg[r] + iv * gv[r][2];
                creg[r] = cn;
                const float hn = ov * fmaxf(cn, 0.f);
                stc(hbuf + (size_t)b * 512 + jj, hn);
                Out[((size_t)b * T_SEQ + t) * 512 + jj] = hn;
            }
        }
        ++eb; gbar(gf, eb, wg, tid);
    }
}

// R10-verbatim pack: WpX row(c) = nt*64+c; WpH gate-interleaved; bsum.
__global__ __launch_bounds__(256)
void pack_w(const float* __restrict__ Wih, const float* __restrict__ Whh,
            const float* __restrict__ bih, const float* __restrict__ bhh,
            u32* __restrict__ WpX, u32* __restrict__ WpH, float* __restrict__ bsum)
{
    __shared__ float tile[64][65];
    const int tid = threadIdx.x;
    const int blk = blockIdx.x;
    if (blk < 16) bsum[blk * 256 + tid] = bih[blk * 256 + tid] + bhh[blk * 256 + tid];

    const int mat = blk & 1;
    const int kc  = (blk >> 1) & 7;
    const int nt  = (blk >> 4) & 31;
    const int l   = blk >> 9;
    const float* W = mat ? Whh : Wih;
    u32* Wp = mat ? WpH : WpX;

    const int c  = tid >> 2;
    const int ko = (tid & 3) * 16;
    const int grow = mat ? ((c & 3) * 512 + nt * 16 + (c >> 2))
                         : (nt * 64 + c);
    const float* src = W + ((size_t)(l * G4 + grow)) * 512 + kc * 64 + ko;
    #pragma unroll
    for (int it = 0; it < 4; ++it) {
        float4 v = ((const float4*)src)[it];
        tile[c][ko + 4*it + 0] = v.x;
        tile[c][ko + 4*it + 1] = v.y;
        tile[c][ko + 4*it + 2] = v.z;
        tile[c][ko + 4*it + 3] = v.w;
    }
    __syncthreads();
    const int kp = tid >> 3;
    const int cb = (tid & 7) * 8;
    u32* dst = Wp + ((size_t)((l * 32 + nt) * 256) + kc * 32 + kp) * 64 + cb;
    #pragma unroll
    for (int j = 0; j < 8; ++j)
        dst[j] = pk2(tile[cb + j][2 * kp], tile[cb + j][2 * kp + 1]);
}

__global__ __launch_bounds__(256)
void init_layer(const float* __restrict__ h0l, float* __restrict__ hbuf,
                u32* __restrict__ flags)
{
    const int idx = blockIdx.x * blockDim.x + threadIdx.x;
    if (idx < 1024) flags[idx] = 0u;
    if (idx < BB * HH) {
        const int b = idx >> 9, j = idx & 511;
        hbuf[idx] = h0l[(size_t)b * 1024 + j];
    }
}

extern "C" void kernel_launch(void* const* d_in, const int* in_sizes, int n_in,
                              void* d_out, int out_size, void* d_ws, size_t ws_size,
                              hipStream_t stream)
{
    const float* x   = (const float*)d_in[0];
    const float* h0  = (const float*)d_in[1];
    const float* c0  = (const float*)d_in[2];
    const float* Wih = (const float*)d_in[3];
    const float* bih = (const float*)d_in[4];
    const float* Whh = (const float*)d_in[5];
    const float* bhh = (const float*)d_in[6];
    float* out = (float*)d_out;
    float* ws  = (float*)d_ws;

    const size_t need_fast =
        (size_t)1024 * 4            // flags
      + (size_t)16384 * 4           // part
      + (size_t)65536 * 4           // hbuf (fp32)
      + (size_t)1048576 * 4 * 2     // WpX + WpH
      + (size_t)4096 * 4            // bsum
      + (size_t)T_SEQ * BB * G4 * 2;// gxbuf f16 (256 MB)

    if (ws_size >= need_fast) {
        u32*   flags = (u32*)ws;                    // 1024 u32
        float* part  = ws + 1024;                   // 16384 f
        float* hbuf  = part + 16384;                // 65536 f
        u32*   WpX   = (u32*)(hbuf + 65536);        // 1048576 u32 (2 layers)
        u32*   WpH   = WpX + 1048576;               // 1048576 u32
        float* bsum  = (float*)(WpH + 1048576);     // 4096 f
        u16*   gxbuf = (u16*)(bsum + 4096);         // 256 MB

        hipLaunchKernelGGL(pack_w, dim3(1024), dim3(256), 0, stream,
                           Wih, Whh, bih, bhh, WpX, WpH, bsum);

        for (int l = 0; l < 2; ++l) {
            hipLaunchKernelGGL(init_layer, dim3(256), dim3(256), 0, stream,
                               h0 + l * 512, hbuf, flags);
            const float* Xin = (l == 0) ? x : (const float*)out;
            hipLaunchKernelGGL(prepass_gx, dim3(65536), dim3(256), 0, stream,
                               Xin, WpX + (size_t)l * 524288, gxbuf);
            const u32*   WpHl = WpH + (size_t)l * 524288;
            const float* bsl  = bsum + l * 2048;
            const float* c0l  = c0 + l * 512;
            const u16*   gxc  = gxbuf;
            void* args[] = {(void*)&gxc, (void*)&WpHl, (void*)&bsl, (void*)&c0l,
                            (void*)&hbuf, (void*)&part, (void*)&flags, (void*)&out};
            hipLaunchCooperativeKernel(reinterpret_cast<void*>(lstm_h),
                                       dim3(128), dim3(NTHR), args, 0, stream);
        }
    } else {
        // R10-verbatim fallback
        u32*   flags = (u32*)ws;                    // 1024 u32
        float* part  = ws + 1024;                   // 16384 f
        float* hbuf  = part + 16384;                // 65536 f
        float* gx    = hbuf + BB * HH;              // 524288 f
        u32*   WpX   = (u32*)(gx + 524288);         // 1048576 u32
        u32*   WpH   = WpX + 1048576;               // 1048576 u32
        float* bsum  = (float*)(WpH + 1048576);     // 4096 f

        hipLaunchKernelGGL(pack_w, dim3(1024), dim3(256), 0, stream,
                           Wih, Whh, bih, bhh, WpX, WpH, bsum);

        for (int l = 0; l < 2; ++l) {
            hipLaunchKernelGGL(init_layer, dim3(256), dim3(256), 0, stream,
                               h0 + l * 512, hbuf, flags);
            const float* Xin  = (l == 0) ? x : (const float*)out;
            const u32*   WpXl = WpX + (size_t)l * 524288;
            const u32*   WpHl = WpH + (size_t)l * 524288;
            const float* bsl  = bsum + l * 2048;
            const float* c0l  = c0 + l * 512;
            void* args[] = {(void*)&Xin, (void*)&WpXl, (void*)&WpHl, (void*)&bsl,
                            (void*)&c0l, (void*)&hbuf, (void*)&gx, (void*)&part,
                            (void*)&flags, (void*)&out};
            hipLaunchCooperativeKernel(reinterpret_cast<void*>(lstm_layer),
                                       dim3(256), dim3(NTHR), args, 0, stream);
        }
    }
}

// Round 16
// 22586.844 us; speedup vs baseline: 1.9523x; 1.3873x over previous
//
#include <hip/hip_runtime.h>

#define T_SEQ 512
#define BB    128
#define HH    512
#define G4    2048
#define KH    512
#define NTHR  256
#define KC    64
#define NCHUNK (KH / KC)   // 8
#define KP    32

typedef unsigned long long u64;
typedef unsigned u32;
typedef unsigned short u16;
typedef __fp16 half2v __attribute__((ext_vector_type(2)));

__device__ __forceinline__ u32 pk2(float a, float b) {
    union { half2v h; u32 u; } t;
    t.h = __builtin_amdgcn_cvt_pkrtz(a, b);
    return t.u;
}
__device__ __forceinline__ float dot2(u32 a, u32 b, float c) {
    union { u32 u; half2v h; } x, y;
    x.u = a; y.u = b;
#if __has_builtin(__builtin_amdgcn_fdot2)
    return __builtin_amdgcn_fdot2(x.h, y.h, c, false);
#else
    return c + (float)x.h.x * (float)y.h.x + (float)x.h.y * (float)y.h.y;
#endif
}
__device__ __forceinline__ u16 f2h(float v) {
    union { __fp16 h; u16 u; } cv; cv.h = (__fp16)v; return cv.u;
}
__device__ __forceinline__ float h2f(u16 v) {
    union { u16 u; __fp16 h; } cv; cv.u = v; return (float)cv.h;
}

// ===== pack Wih (R14-proven layout, WpX only) + bsum ========================
// WpX_u32[l][nt][kp][c] = pack_f16(Wih[nt*64+c][2kp..2kp+1]);  bsum=bih+bhh.
__global__ __launch_bounds__(256)
void pack_wx(const float* __restrict__ Wih,
             const float* __restrict__ bih, const float* __restrict__ bhh,
             u32* __restrict__ WpX, float* __restrict__ bsum)
{
    __shared__ float tile[64][65];
    const int tid = threadIdx.x;
    const int blk = blockIdx.x;          // 0..511
    if (blk < 16) bsum[blk * 256 + tid] = bih[blk * 256 + tid] + bhh[blk * 256 + tid];

    const int kc = blk & 7;
    const int nt = (blk >> 3) & 31;
    const int l  = blk >> 8;

    const int c  = tid >> 2;
    const int ko = (tid & 3) * 16;
    const int grow = nt * 64 + c;
    const float* src = Wih + ((size_t)(l * G4 + grow)) * 512 + kc * 64 + ko;
    #pragma unroll
    for (int it = 0; it < 4; ++it) {
        float4 v = ((const float4*)src)[it];
        tile[c][ko + 4*it + 0] = v.x;
        tile[c][ko + 4*it + 1] = v.y;
        tile[c][ko + 4*it + 2] = v.z;
        tile[c][ko + 4*it + 3] = v.w;
    }
    __syncthreads();
    const int kp = tid >> 3;
    const int cb = (tid & 7) * 8;
    u32* dst = WpX + ((size_t)((l * 32 + nt) * 256) + kc * 32 + kp) * 64 + cb;
    #pragma unroll
    for (int j = 0; j < 8; ++j)
        dst[j] = pk2(tile[cb + j][2 * kp], tile[cb + j][2 * kp + 1]);
}

// ===== pack Whh lane-major for the row-owner recurrence =====================
// Wp2 uint4[(l*16+kc)*16 + g*4 + j][tp] = Whh[l][g*512+tp][kc*32+j*8 .. +7] (f16 pairs)
// NOTE: needs 2^18 threads (l is bit 17) -> grid 1024 x 256. R15 launched 512
// blocks, leaving layer 1 unpacked (0xAA garbage weights) -> absmax 1.22.
__global__ __launch_bounds__(256)
void pack_wh2(const float* __restrict__ Whh, u32* __restrict__ Wp2)
{
    const int flat = blockIdx.x * 256 + threadIdx.x;   // 0..262143
    const int tp = flat & 511;
    const int j  = (flat >> 9) & 3;
    const int g  = (flat >> 11) & 3;
    const int kc = (flat >> 13) & 15;
    const int l  = (flat >> 17) & 1;
    const float* src = Whh + ((size_t)(l * G4 + g * 512 + tp)) * 512 + kc * 32 + j * 8;
    float4 a = ((const float4*)src)[0];
    float4 b = ((const float4*)src)[1];
    u32* dst = Wp2 + ((size_t)(((l * 16 + kc) * 4 + g) * 4 + j) * 512 + tp) * 4;
    dst[0] = pk2(a.x, a.y); dst[1] = pk2(a.z, a.w);
    dst[2] = pk2(b.x, b.y); dst[3] = pk2(b.z, b.w);
}

// ===== Prepass (R14-proven): gxbuf[t][b][2048] f16 = Xin[b][t] @ Wih^T ======
__global__ __launch_bounds__(NTHR)
void prepass_gx(const float* __restrict__ Xin,
                const u32* __restrict__ WpXl,
                u16* __restrict__ gxbuf)
{
    __shared__ u32 As2[KP][34];
    __shared__ u32 Bs[KP * 64];
    const int tid = threadIdx.x;
    const int blk = blockIdx.x;
    const int nt = blk & 31;
    const int tg = (blk >> 5) & 15;
    const int b  = blk >> 9;
    const int t0 = tg * 32;
    const int xr = tid >> 4, xc4 = tid & 15;
    const int ty = tid >> 4, tx = tid & 15;
    const u32* Wp = WpXl + (size_t)nt * (256 * 64);
    const float* Ab = Xin + ((size_t)b * T_SEQ + t0) * 512;

    float4 vaX[2][2];
    uint4  vb16[2];
    float acc[2][4] = {};

    auto loadA = [&](int c, int s) {
        #pragma unroll
        for (int it = 0; it < 2; ++it)
            vaX[s][it] = *(const float4*)(Ab + (size_t)(xr + 16*it) * 512 + c * KC + 4 * xc4);
    };
    auto loadB = [&](int c) {
        const uint4* q = (const uint4*)(Wp + (size_t)c * (KP * 64));
        vb16[0] = q[tid];
        vb16[1] = q[tid + 256];
    };

    loadA(0, 0);
    loadB(0);
    loadA(1, 1);
    for (int c = 0; c < NCHUNK; ++c) {
        __syncthreads();
        #pragma unroll
        for (int it = 0; it < 2; ++it) {
            const float4 v = vaX[c & 1][it];
            As2[2*xc4+0][xr+16*it] = pk2(v.x, v.y);
            As2[2*xc4+1][xr+16*it] = pk2(v.z, v.w);
        }
        ((uint4*)Bs)[tid]       = vb16[0];
        ((uint4*)Bs)[tid + 256] = vb16[1];
        __syncthreads();
        if (c + 2 < NCHUNK) loadA(c + 2, c & 1);
        if (c + 1 < NCHUNK) loadB(c + 1);
        #pragma unroll
        for (int kp = 0; kp < KP; ++kp) {
            uint2 a = *(const uint2*)&As2[kp][2 * ty];
            uint4 bq = *(const uint4*)&Bs[kp * 64 + 4 * tx];
            acc[0][0] = dot2(a.x, bq.x, acc[0][0]);
            acc[0][1] = dot2(a.x, bq.y, acc[0][1]);
            acc[0][2] = dot2(a.x, bq.z, acc[0][2]);
            acc[0][3] = dot2(a.x, bq.w, acc[0][3]);
            acc[1][0] = dot2(a.y, bq.x, acc[1][0]);
            acc[1][1] = dot2(a.y, bq.y, acc[1][1]);
            acc[1][2] = dot2(a.y, bq.z, acc[1][2]);
            acc[1][3] = dot2(a.y, bq.w, acc[1][3]);
        }
    }
    #pragma unroll
    for (int r = 0; r < 2; ++r) {
        const int t = t0 + 2 * ty + r;
        const u64 w = (u64)f2h(acc[r][0])
                    | ((u64)f2h(acc[r][1]) << 16)
                    | ((u64)f2h(acc[r][2]) << 32)
                    | ((u64)f2h(acc[r][3]) << 48);
        *(u64*)(gxbuf + ((size_t)t * BB + b) * G4 + nt * 64 + 4 * tx) = w;
    }
}

// ===== Row-owner recurrence: 64 blocks x 512 thr, ZERO inter-block sync =====
// Block bid owns batch rows {2bid, 2bid+1} end-to-end: all 2048 gate cols,
// L1 norms block-local (shfl + LDS), c in regs, h in LDS (f16).
// Thread tid owns gate col tid of each gate: cols {g*512+tid}.
// Weights streamed from L2 (same 2 MB for all blocks -> one copy per XCD L2).
__global__ __launch_bounds__(512, 2)
void lstm_rec2(const u16* __restrict__ gxbuf,
               const u32* __restrict__ Wp2l,    // [16][4][4][512] uint4
               const float* __restrict__ bsl,   // [2048]
               const float* __restrict__ c0l,   // idx row*1024 + j
               const float* __restrict__ h0l,   // idx row*1024 + j
               float* __restrict__ Out)         // [B][T][512]
{
    __shared__ __align__(16) u16 hsh[2][512];
    __shared__ float red[8][8];

    const int tid = threadIdx.x;     // 0..511
    const int bid = blockIdx.x;      // 0..63
    const int row0 = bid * 2;

    float c[2], bv[4];
    c[0] = c0l[(size_t)(row0 + 0) * 1024 + tid];
    c[1] = c0l[(size_t)(row0 + 1) * 1024 + tid];
    #pragma unroll
    for (int g = 0; g < 4; ++g) bv[g] = bsl[g * 512 + tid];
    hsh[0][tid] = f2h(h0l[(size_t)(row0 + 0) * 1024 + tid]);
    hsh[1][tid] = f2h(h0l[(size_t)(row0 + 1) * 1024 + tid]);
    __syncthreads();

    const uint4* Wq = (const uint4*)Wp2l;

    uint4 wc[16], wn[16];
    #pragma unroll
    for (int i = 0; i < 16; ++i) wc[i] = Wq[(size_t)i * 512 + tid];

    for (int t = 0; t < T_SEQ; ++t) {
        // gx loads issued early; consumed after the GEMM
        const u16* gp = gxbuf + ((size_t)t * BB + row0) * G4;
        float gxv[2][4];
        #pragma unroll
        for (int r = 0; r < 2; ++r)
            #pragma unroll
            for (int g = 0; g < 4; ++g)
                gxv[r][g] = h2f(gp[(size_t)r * G4 + g * 512 + tid]);

        float acc[2][4] = {};

        #define COMPUTE_CHUNK(KCC, WREG)                                     \
        {                                                                    \
            u32 hr[2][16];                                                   \
            _Pragma("unroll")                                                \
            for (int r = 0; r < 2; ++r) {                                    \
                _Pragma("unroll")                                            \
                for (int q = 0; q < 4; ++q)                                  \
                    *(uint4*)&hr[r][q * 4] =                                 \
                        *(const uint4*)&((const u32*)hsh[r])[(KCC) * 16 + q * 4]; \
            }                                                                \
            _Pragma("unroll")                                                \
            for (int g = 0; g < 4; ++g) {                                    \
                _Pragma("unroll")                                            \
                for (int j = 0; j < 4; ++j) {                                \
                    const uint4 w = WREG[g * 4 + j];                         \
                    _Pragma("unroll")                                        \
                    for (int r = 0; r < 2; ++r) {                            \
                        acc[r][g] = dot2(hr[r][j*4+0], w.x, acc[r][g]);      \
                        acc[r][g] = dot2(hr[r][j*4+1], w.y, acc[r][g]);      \
                        acc[r][g] = dot2(hr[r][j*4+2], w.z, acc[r][g]);      \
                        acc[r][g] = dot2(hr[r][j*4+3], w.w, acc[r][g]);      \
                    }                                                        \
                }                                                            \
            }                                                                \
        }

        #pragma unroll 1
        for (int kc = 0; kc < 16; kc += 2) {
            #pragma unroll
            for (int i = 0; i < 16; ++i)
                wn[i] = Wq[(size_t)((kc + 1) * 16 + i) * 512 + tid];
            COMPUTE_CHUNK(kc, wc)
            #pragma unroll
            for (int i = 0; i < 16; ++i)
                wc[i] = Wq[(size_t)((((kc + 2) & 15)) * 16 + i) * 512 + tid];
            COMPUTE_CHUNK(kc + 1, wn)
        }
        #undef COMPUTE_CHUNK

        // gates + block-local L1 norms
        float gv[2][4], pv[6];
        #pragma unroll
        for (int r = 0; r < 2; ++r) {
            #pragma unroll
            for (int g = 0; g < 4; ++g) gv[r][g] = acc[r][g] + gxv[r][g] + bv[g];
            pv[r*3+0] = fabsf(gv[r][0]);
            pv[r*3+1] = fabsf(gv[r][1]);
            pv[r*3+2] = fabsf(gv[r][3]);
        }
        #pragma unroll
        for (int d = 1; d < 64; d <<= 1)
            #pragma unroll
            for (int q = 0; q < 6; ++q) pv[q] += __shfl_xor(pv[q], d);
        const int wv = tid >> 6;
        if ((tid & 63) == 0) {
            #pragma unroll
            for (int q = 0; q < 6; ++q) red[wv][q] = pv[q];
        }
        __syncthreads();   // also: all GEMM reads of hsh are done past here
        float S[6];
        #pragma unroll
        for (int q = 0; q < 6; ++q) {
            float s = 0.f;
            #pragma unroll
            for (int w = 0; w < 8; ++w) s += red[w][q];
            S[q] = fmaxf(s, 1e-12f);
        }
        #pragma unroll
        for (int r = 0; r < 2; ++r) {
            const float iv = 1.f / (1.f + expf(-gv[r][0] / S[r*3+0]));
            const float fv = 1.f / (1.f + expf(-gv[r][1] / S[r*3+1]));
            const float ov = 1.f / (1.f + expf(-gv[r][3] / S[r*3+2]));
            const float cn = fv * c[r] + iv * gv[r][2];
            c[r] = cn;
            const float hn = ov * fmaxf(cn, 0.f);
            Out[((size_t)(row0 + r) * T_SEQ + t) * 512 + tid] = hn;
            hsh[r][tid] = f2h(hn);
        }
        __syncthreads();   // h(t) visible to next step's GEMM
    }
}

extern "C" void kernel_launch(void* const* d_in, const int* in_sizes, int n_in,
                              void* d_out, int out_size, void* d_ws, size_t ws_size,
                              hipStream_t stream)
{
    const float* x   = (const float*)d_in[0];
    const float* h0  = (const float*)d_in[1];
    const float* c0  = (const float*)d_in[2];
    const float* Wih = (const float*)d_in[3];
    const float* bih = (const float*)d_in[4];
    const float* Whh = (const float*)d_in[5];
    const float* bhh = (const float*)d_in[6];
    float* out = (float*)d_out;
    float* ws  = (float*)d_ws;

    // ws layout BYTE-IDENTICAL to R14's proven fast path (Wp2 replaces WpH):
    // flags/part/hbuf regions retained (unused) to keep offsets proven-safe.
    float* part  = ws + 1024;                   // (unused)
    float* hbuf  = part + 16384;                // (unused)
    u32*   WpX   = (u32*)(hbuf + 65536);        // 1048576 u32 (2 layers)
    u32*   Wp2   = WpX + 1048576;               // 1048576 u32 (2 layers)
    float* bsum  = (float*)(Wp2 + 1048576);     // 4096 f
    u16*   gxbuf = (u16*)(bsum + 4096);         // 256 MB
    (void)ws_size;

    hipLaunchKernelGGL(pack_wx, dim3(512), dim3(256), 0, stream,
                       Wih, bih, bhh, WpX, bsum);
    hipLaunchKernelGGL(pack_wh2, dim3(1024), dim3(256), 0, stream,
                       Whh, Wp2);   // FIXED: was 512 blocks -> layer 1 unpacked

    for (int l = 0; l < 2; ++l) {
        const float* Xin = (l == 0) ? x : (const float*)out;
        hipLaunchKernelGGL(prepass_gx, dim3(65536), dim3(256), 0, stream,
                           Xin, WpX + (size_t)l * 524288, gxbuf);
        hipLaunchKernelGGL(lstm_rec2, dim3(64), dim3(512), 0, stream,
                           gxbuf, Wp2 + (size_t)l * 524288,
                           bsum + l * 2048, c0 + l * 512, h0 + l * 512, out);
    }
}

// Round 17
// 21400.735 us; speedup vs baseline: 2.0605x; 1.0554x over previous
//
#include <hip/hip_runtime.h>

#define T_SEQ 512
#define BB    128
#define HH    512
#define G4    2048
#define KH    512
#define NTHR  256
#define KC    64
#define NCHUNK (KH / KC)   // 8
#define KP    32

typedef unsigned long long u64;
typedef unsigned u32;
typedef unsigned short u16;
typedef __fp16 half2v __attribute__((ext_vector_type(2)));

__device__ __forceinline__ u32 pk2(float a, float b) {
    union { half2v h; u32 u; } t;
    t.h = __builtin_amdgcn_cvt_pkrtz(a, b);
    return t.u;
}
__device__ __forceinline__ float dot2(u32 a, u32 b, float c) {
    union { u32 u; half2v h; } x, y;
    x.u = a; y.u = b;
#if __has_builtin(__builtin_amdgcn_fdot2)
    return __builtin_amdgcn_fdot2(x.h, y.h, c, false);
#else
    return c + (float)x.h.x * (float)y.h.x + (float)x.h.y * (float)y.h.y;
#endif
}
__device__ __forceinline__ u16 f2h(float v) {
    union { __fp16 h; u16 u; } cv; cv.h = (__fp16)v; return cv.u;
}
__device__ __forceinline__ float h2f(u16 v) {
    union { u16 u; __fp16 h; } cv; cv.u = v; return (float)cv.h;
}

// ===== pack Wih (proven) + bsum =============================================
__global__ __launch_bounds__(256)
void pack_wx(const float* __restrict__ Wih,
             const float* __restrict__ bih, const float* __restrict__ bhh,
             u32* __restrict__ WpX, float* __restrict__ bsum)
{
    __shared__ float tile[64][65];
    const int tid = threadIdx.x;
    const int blk = blockIdx.x;          // 0..511
    if (blk < 16) bsum[blk * 256 + tid] = bih[blk * 256 + tid] + bhh[blk * 256 + tid];

    const int kc = blk & 7;
    const int nt = (blk >> 3) & 31;
    const int l  = blk >> 8;

    const int c  = tid >> 2;
    const int ko = (tid & 3) * 16;
    const int grow = nt * 64 + c;
    const float* src = Wih + ((size_t)(l * G4 + grow)) * 512 + kc * 64 + ko;
    #pragma unroll
    for (int it = 0; it < 4; ++it) {
        float4 v = ((const float4*)src)[it];
        tile[c][ko + 4*it + 0] = v.x;
        tile[c][ko + 4*it + 1] = v.y;
        tile[c][ko + 4*it + 2] = v.z;
        tile[c][ko + 4*it + 3] = v.w;
    }
    __syncthreads();
    const int kp = tid >> 3;
    const int cb = (tid & 7) * 8;
    u32* dst = WpX + ((size_t)((l * 32 + nt) * 256) + kc * 32 + kp) * 64 + cb;
    #pragma unroll
    for (int j = 0; j < 8; ++j)
        dst[j] = pk2(tile[cb + j][2 * kp], tile[cb + j][2 * kp + 1]);
}

// ===== pack Whh lane-major (proven; 2^18 threads -> grid 1024) ==============
__global__ __launch_bounds__(256)
void pack_wh2(const float* __restrict__ Whh, u32* __restrict__ Wp2)
{
    const int flat = blockIdx.x * 256 + threadIdx.x;   // 0..262143
    const int tp = flat & 511;
    const int j  = (flat >> 9) & 3;
    const int g  = (flat >> 11) & 3;
    const int kc = (flat >> 13) & 15;
    const int l  = (flat >> 17) & 1;
    const float* src = Whh + ((size_t)(l * G4 + g * 512 + tp)) * 512 + kc * 32 + j * 8;
    float4 a = ((const float4*)src)[0];
    float4 b = ((const float4*)src)[1];
    u32* dst = Wp2 + ((size_t)(((l * 16 + kc) * 4 + g) * 4 + j) * 512 + tp) * 4;
    dst[0] = pk2(a.x, a.y); dst[1] = pk2(a.z, a.w);
    dst[2] = pk2(b.x, b.y); dst[3] = pk2(b.z, b.w);
}

// ===== Prepass (proven): gxbuf[t][b][2048] f16 = Xin[b][t] @ Wih^T ==========
__global__ __launch_bounds__(NTHR)
void prepass_gx(const float* __restrict__ Xin,
                const u32* __restrict__ WpXl,
                u16* __restrict__ gxbuf)
{
    __shared__ u32 As2[KP][34];
    __shared__ u32 Bs[KP * 64];
    const int tid = threadIdx.x;
    const int blk = blockIdx.x;
    const int nt = blk & 31;
    const int tg = (blk >> 5) & 15;
    const int b  = blk >> 9;
    const int t0 = tg * 32;
    const int xr = tid >> 4, xc4 = tid & 15;
    const int ty = tid >> 4, tx = tid & 15;
    const u32* Wp = WpXl + (size_t)nt * (256 * 64);
    const float* Ab = Xin + ((size_t)b * T_SEQ + t0) * 512;

    float4 vaX[2][2];
    uint4  vb16[2];
    float acc[2][4] = {};

    auto loadA = [&](int c, int s) {
        #pragma unroll
        for (int it = 0; it < 2; ++it)
            vaX[s][it] = *(const float4*)(Ab + (size_t)(xr + 16*it) * 512 + c * KC + 4 * xc4);
    };
    auto loadB = [&](int c) {
        const uint4* q = (const uint4*)(Wp + (size_t)c * (KP * 64));
        vb16[0] = q[tid];
        vb16[1] = q[tid + 256];
    };

    loadA(0, 0);
    loadB(0);
    loadA(1, 1);
    for (int c = 0; c < NCHUNK; ++c) {
        __syncthreads();
        #pragma unroll
        for (int it = 0; it < 2; ++it) {
            const float4 v = vaX[c & 1][it];
            As2[2*xc4+0][xr+16*it] = pk2(v.x, v.y);
            As2[2*xc4+1][xr+16*it] = pk2(v.z, v.w);
        }
        ((uint4*)Bs)[tid]       = vb16[0];
        ((uint4*)Bs)[tid + 256] = vb16[1];
        __syncthreads();
        if (c + 2 < NCHUNK) loadA(c + 2, c & 1);
        if (c + 1 < NCHUNK) loadB(c + 1);
        #pragma unroll
        for (int kp = 0; kp < KP; ++kp) {
            uint2 a = *(const uint2*)&As2[kp][2 * ty];
            uint4 bq = *(const uint4*)&Bs[kp * 64 + 4 * tx];
            acc[0][0] = dot2(a.x, bq.x, acc[0][0]);
            acc[0][1] = dot2(a.x, bq.y, acc[0][1]);
            acc[0][2] = dot2(a.x, bq.z, acc[0][2]);
            acc[0][3] = dot2(a.x, bq.w, acc[0][3]);
            acc[1][0] = dot2(a.y, bq.x, acc[1][0]);
            acc[1][1] = dot2(a.y, bq.y, acc[1][1]);
            acc[1][2] = dot2(a.y, bq.z, acc[1][2]);
            acc[1][3] = dot2(a.y, bq.w, acc[1][3]);
        }
    }
    #pragma unroll
    for (int r = 0; r < 2; ++r) {
        const int t = t0 + 2 * ty + r;
        const u64 w = (u64)f2h(acc[r][0])
                    | ((u64)f2h(acc[r][1]) << 16)
                    | ((u64)f2h(acc[r][2]) << 32)
                    | ((u64)f2h(acc[r][3]) << 48);
        *(u64*)(gxbuf + ((size_t)t * BB + b) * G4 + nt * 64 + 4 * tx) = w;
    }
}

// ===== Row-owner recurrence: 128 blocks x 512 thr, ONE row per block ========
// Zero inter-block sync (R16-proven protocol). Block bid owns batch row bid:
// all 2048 gate cols, norms block-local, c in regs, h in LDS (f16).
// Thread tid owns gate col tid of each of the 4 gates.
// 1 row/block halves per-thread VALU and per-CU LDS traffic vs R16 and
// doubles active CUs (128); L2 weight stream doubles (expected new bound).
__global__ __launch_bounds__(512, 2)
void lstm_rec2(const u16* __restrict__ gxbuf,
               const u32* __restrict__ Wp2l,    // [16][4][4][512] uint4
               const float* __restrict__ bsl,   // [2048]
               const float* __restrict__ c0l,   // idx row*1024 + j
               const float* __restrict__ h0l,   // idx row*1024 + j
               float* __restrict__ Out)         // [B][T][512]
{
    __shared__ __align__(16) u16 hsh[512];
    __shared__ float red[8][8];

    const int tid = threadIdx.x;     // 0..511
    const int row = blockIdx.x;      // 0..127

    float cst, bv[4];
    cst = c0l[(size_t)row * 1024 + tid];
    #pragma unroll
    for (int g = 0; g < 4; ++g) bv[g] = bsl[g * 512 + tid];
    hsh[tid] = f2h(h0l[(size_t)row * 1024 + tid]);
    __syncthreads();

    const uint4* Wq = (const uint4*)Wp2l;

    uint4 wc[16], wn[16];
    #pragma unroll
    for (int i = 0; i < 16; ++i) wc[i] = Wq[(size_t)i * 512 + tid];

    for (int t = 0; t < T_SEQ; ++t) {
        // gx loads issued early; consumed after the GEMM
        const u16* gp = gxbuf + ((size_t)t * BB + row) * G4;
        float gxv[4];
        #pragma unroll
        for (int g = 0; g < 4; ++g) gxv[g] = h2f(gp[(size_t)g * 512 + tid]);

        float acc[4] = {0.f, 0.f, 0.f, 0.f};

        #define COMPUTE_CHUNK(KCC, WREG)                                     \
        {                                                                    \
            u32 hr[16];                                                      \
            _Pragma("unroll")                                                \
            for (int q = 0; q < 4; ++q)                                      \
                *(uint4*)&hr[q * 4] =                                        \
                    *(const uint4*)&((const u32*)hsh)[(KCC) * 16 + q * 4];   \
            _Pragma("unroll")                                                \
            for (int g = 0; g < 4; ++g) {                                    \
                _Pragma("unroll")                                            \
                for (int j = 0; j < 4; ++j) {                                \
                    const uint4 w = WREG[g * 4 + j];                         \
                    acc[g] = dot2(hr[j*4+0], w.x, acc[g]);                   \
                    acc[g] = dot2(hr[j*4+1], w.y, acc[g]);                   \
                    acc[g] = dot2(hr[j*4+2], w.z, acc[g]);                   \
                    acc[g] = dot2(hr[j*4+3], w.w, acc[g]);                   \
                }                                                            \
            }                                                                \
        }

        #pragma unroll 1
        for (int kc = 0; kc < 16; kc += 2) {
            #pragma unroll
            for (int i = 0; i < 16; ++i)
                wn[i] = Wq[(size_t)((kc + 1) * 16 + i) * 512 + tid];
            COMPUTE_CHUNK(kc, wc)
            #pragma unroll
            for (int i = 0; i < 16; ++i)
                wc[i] = Wq[(size_t)((((kc + 2) & 15)) * 16 + i) * 512 + tid];
            COMPUTE_CHUNK(kc + 1, wn)
        }
        #undef COMPUTE_CHUNK

        // gates + block-local L1 norms
        float gv[4], pv[3];
        #pragma unroll
        for (int g = 0; g < 4; ++g) gv[g] = acc[g] + gxv[g] + bv[g];
        pv[0] = fabsf(gv[0]);
        pv[1] = fabsf(gv[1]);
        pv[2] = fabsf(gv[3]);
        #pragma unroll
        for (int d = 1; d < 64; d <<= 1)
            #pragma unroll
            for (int q = 0; q < 3; ++q) pv[q] += __shfl_xor(pv[q], d);
        const int wv = tid >> 6;
        if ((tid & 63) == 0) {
            #pragma unroll
            for (int q = 0; q < 3; ++q) red[wv][q] = pv[q];
        }
        __syncthreads();   // also: all GEMM reads of hsh are done past here
        float S[3];
        #pragma unroll
        for (int q = 0; q < 3; ++q) {
            float s = 0.f;
            #pragma unroll
            for (int w = 0; w < 8; ++w) s += red[w][q];
            S[q] = fmaxf(s, 1e-12f);
        }
        const float iv = 1.f / (1.f + expf(-gv[0] / S[0]));
        const float fv = 1.f / (1.f + expf(-gv[1] / S[1]));
        const float ov = 1.f / (1.f + expf(-gv[3] / S[2]));
        const float cn = fv * cst + iv * gv[2];
        cst = cn;
        const float hn = ov * fmaxf(cn, 0.f);
        Out[((size_t)row * T_SEQ + t) * 512 + tid] = hn;
        hsh[tid] = f2h(hn);
        __syncthreads();   // h(t) visible to next step's GEMM
    }
}

extern "C" void kernel_launch(void* const* d_in, const int* in_sizes, int n_in,
                              void* d_out, int out_size, void* d_ws, size_t ws_size,
                              hipStream_t stream)
{
    const float* x   = (const float*)d_in[0];
    const float* h0  = (const float*)d_in[1];
    const float* c0  = (const float*)d_in[2];
    const float* Wih = (const float*)d_in[3];
    const float* bih = (const float*)d_in[4];
    const float* Whh = (const float*)d_in[5];
    const float* bhh = (const float*)d_in[6];
    float* out = (float*)d_out;
    float* ws  = (float*)d_ws;

    // ws layout identical to R16 (proven)
    float* part  = ws + 1024;                   // (unused)
    float* hbuf  = part + 16384;                // (unused)
    u32*   WpX   = (u32*)(hbuf + 65536);        // 1048576 u32 (2 layers)
    u32*   Wp2   = WpX + 1048576;               // 1048576 u32 (2 layers)
    float* bsum  = (float*)(Wp2 + 1048576);     // 4096 f
    u16*   gxbuf = (u16*)(bsum + 4096);         // 256 MB
    (void)ws_size;

    hipLaunchKernelGGL(pack_wx, dim3(512), dim3(256), 0, stream,
                       Wih, bih, bhh, WpX, bsum);
    hipLaunchKernelGGL(pack_wh2, dim3(1024), dim3(256), 0, stream,
                       Whh, Wp2);

    for (int l = 0; l < 2; ++l) {
        const float* Xin = (l == 0) ? x : (const float*)out;
        hipLaunchKernelGGL(prepass_gx, dim3(65536), dim3(256), 0, stream,
                           Xin, WpX + (size_t)l * 524288, gxbuf);
        hipLaunchKernelGGL(lstm_rec2, dim3(128), dim3(512), 0, stream,
                           gxbuf, Wp2 + (size_t)l * 524288,
                           bsum + l * 2048, c0 + l * 512, h0 + l * 512, out);
    }
}

// Round 18
// 21365.320 us; speedup vs baseline: 2.0639x; 1.0017x over previous
//
#include <hip/hip_runtime.h>

#define T_SEQ 512
#define BB    128
#define HH    512
#define G4    2048
#define KH    512
#define NTHR  256
#define KC    64
#define NCHUNK (KH / KC)   // 8
#define KP    32

typedef unsigned long long u64;
typedef unsigned u32;
typedef unsigned short u16;
typedef __fp16 half2v __attribute__((ext_vector_type(2)));

__device__ __forceinline__ u32 pk2(float a, float b) {
    union { half2v h; u32 u; } t;
    t.h = __builtin_amdgcn_cvt_pkrtz(a, b);
    return t.u;
}
__device__ __forceinline__ float dot2(u32 a, u32 b, float c) {
    union { u32 u; half2v h; } x, y;
    x.u = a; y.u = b;
#if __has_builtin(__builtin_amdgcn_fdot2)
    return __builtin_amdgcn_fdot2(x.h, y.h, c, false);
#else
    return c + (float)x.h.x * (float)y.h.x + (float)x.h.y * (float)y.h.y;
#endif
}
__device__ __forceinline__ u16 f2h(float v) {
    union { __fp16 h; u16 u; } cv; cv.h = (__fp16)v; return cv.u;
}
__device__ __forceinline__ float h2f(u16 v) {
    union { u16 u; __fp16 h; } cv; cv.u = v; return (float)cv.h;
}

// ===== pack Wih (proven) + bsum =============================================
__global__ __launch_bounds__(256)
void pack_wx(const float* __restrict__ Wih,
             const float* __restrict__ bih, const float* __restrict__ bhh,
             u32* __restrict__ WpX, float* __restrict__ bsum)
{
    __shared__ float tile[64][65];
    const int tid = threadIdx.x;
    const int blk = blockIdx.x;          // 0..511
    if (blk < 16) bsum[blk * 256 + tid] = bih[blk * 256 + tid] + bhh[blk * 256 + tid];

    const int kc = blk & 7;
    const int nt = (blk >> 3) & 31;
    const int l  = blk >> 8;

    const int c  = tid >> 2;
    const int ko = (tid & 3) * 16;
    const int grow = nt * 64 + c;
    const float* src = Wih + ((size_t)(l * G4 + grow)) * 512 + kc * 64 + ko;
    #pragma unroll
    for (int it = 0; it < 4; ++it) {
        float4 v = ((const float4*)src)[it];
        tile[c][ko + 4*it + 0] = v.x;
        tile[c][ko + 4*it + 1] = v.y;
        tile[c][ko + 4*it + 2] = v.z;
        tile[c][ko + 4*it + 3] = v.w;
    }
    __syncthreads();
    const int kp = tid >> 3;
    const int cb = (tid & 7) * 8;
    u32* dst = WpX + ((size_t)((l * 32 + nt) * 256) + kc * 32 + kp) * 64 + cb;
    #pragma unroll
    for (int j = 0; j < 8; ++j)
        dst[j] = pk2(tile[cb + j][2 * kp], tile[cb + j][2 * kp + 1]);
}

// ===== pack Whh lane-major (proven; 2^18 threads -> grid 1024) ==============
__global__ __launch_bounds__(256)
void pack_wh2(const float* __restrict__ Whh, u32* __restrict__ Wp2)
{
    const int flat = blockIdx.x * 256 + threadIdx.x;   // 0..262143
    const int tp = flat & 511;
    const int j  = (flat >> 9) & 3;
    const int g  = (flat >> 11) & 3;
    const int kc = (flat >> 13) & 15;
    const int l  = (flat >> 17) & 1;
    const float* src = Whh + ((size_t)(l * G4 + g * 512 + tp)) * 512 + kc * 32 + j * 8;
    float4 a = ((const float4*)src)[0];
    float4 b = ((const float4*)src)[1];
    u32* dst = Wp2 + ((size_t)(((l * 16 + kc) * 4 + g) * 4 + j) * 512 + tp) * 4;
    dst[0] = pk2(a.x, a.y); dst[1] = pk2(a.z, a.w);
    dst[2] = pk2(b.x, b.y); dst[3] = pk2(b.z, b.w);
}

// ===== Prepass (proven): gxbuf[t][b][2048] f16 = Xin[b][t] @ Wih^T ==========
__global__ __launch_bounds__(NTHR)
void prepass_gx(const float* __restrict__ Xin,
                const u32* __restrict__ WpXl,
                u16* __restrict__ gxbuf)
{
    __shared__ u32 As2[KP][34];
    __shared__ u32 Bs[KP * 64];
    const int tid = threadIdx.x;
    const int blk = blockIdx.x;
    const int nt = blk & 31;
    const int tg = (blk >> 5) & 15;
    const int b  = blk >> 9;
    const int t0 = tg * 32;
    const int xr = tid >> 4, xc4 = tid & 15;
    const int ty = tid >> 4, tx = tid & 15;
    const u32* Wp = WpXl + (size_t)nt * (256 * 64);
    const float* Ab = Xin + ((size_t)b * T_SEQ + t0) * 512;

    float4 vaX[2][2];
    uint4  vb16[2];
    float acc[2][4] = {};

    auto loadA = [&](int c, int s) {
        #pragma unroll
        for (int it = 0; it < 2; ++it)
            vaX[s][it] = *(const float4*)(Ab + (size_t)(xr + 16*it) * 512 + c * KC + 4 * xc4);
    };
    auto loadB = [&](int c) {
        const uint4* q = (const uint4*)(Wp + (size_t)c * (KP * 64));
        vb16[0] = q[tid];
        vb16[1] = q[tid + 256];
    };

    loadA(0, 0);
    loadB(0);
    loadA(1, 1);
    for (int c = 0; c < NCHUNK; ++c) {
        __syncthreads();
        #pragma unroll
        for (int it = 0; it < 2; ++it) {
            const float4 v = vaX[c & 1][it];
            As2[2*xc4+0][xr+16*it] = pk2(v.x, v.y);
            As2[2*xc4+1][xr+16*it] = pk2(v.z, v.w);
        }
        ((uint4*)Bs)[tid]       = vb16[0];
        ((uint4*)Bs)[tid + 256] = vb16[1];
        __syncthreads();
        if (c + 2 < NCHUNK) loadA(c + 2, c & 1);
        if (c + 1 < NCHUNK) loadB(c + 1);
        #pragma unroll
        for (int kp = 0; kp < KP; ++kp) {
            uint2 a = *(const uint2*)&As2[kp][2 * ty];
            uint4 bq = *(const uint4*)&Bs[kp * 64 + 4 * tx];
            acc[0][0] = dot2(a.x, bq.x, acc[0][0]);
            acc[0][1] = dot2(a.x, bq.y, acc[0][1]);
            acc[0][2] = dot2(a.x, bq.z, acc[0][2]);
            acc[0][3] = dot2(a.x, bq.w, acc[0][3]);
            acc[1][0] = dot2(a.y, bq.x, acc[1][0]);
            acc[1][1] = dot2(a.y, bq.y, acc[1][1]);
            acc[1][2] = dot2(a.y, bq.z, acc[1][2]);
            acc[1][3] = dot2(a.y, bq.w, acc[1][3]);
        }
    }
    #pragma unroll
    for (int r = 0; r < 2; ++r) {
        const int t = t0 + 2 * ty + r;
        const u64 w = (u64)f2h(acc[r][0])
                    | ((u64)f2h(acc[r][1]) << 16)
                    | ((u64)f2h(acc[r][2]) << 32)
                    | ((u64)f2h(acc[r][3]) << 48);
        *(u64*)(gxbuf + ((size_t)t * BB + b) * G4 + nt * 64 + 4 * tx) = w;
    }
}

// ===== Row-owner recurrence: 128 blocks x 512 thr, ONE row per block ========
// Zero inter-block sync (proven). ONLY change vs R17: __launch_bounds__(512,1)
// -> VGPR cap 256 (was 128), so the wc[16]+wn[16] double-buffer ring (128
// VGPRs) is actually register-resident and next-chunk loads overlap compute.
// (R17's VGPR_Count=80 proved the compiler serialized the ring under the cap.)
// Residency unchanged: 128 blocks on 256 CUs = 1 block/CU either way.
__global__ __launch_bounds__(512, 1)
void lstm_rec2(const u16* __restrict__ gxbuf,
               const u32* __restrict__ Wp2l,    // [16][4][4][512] uint4
               const float* __restrict__ bsl,   // [2048]
               const float* __restrict__ c0l,   // idx row*1024 + j
               const float* __restrict__ h0l,   // idx row*1024 + j
               float* __restrict__ Out)         // [B][T][512]
{
    __shared__ __align__(16) u16 hsh[512];
    __shared__ float red[8][8];

    const int tid = threadIdx.x;     // 0..511
    const int row = blockIdx.x;      // 0..127

    float cst, bv[4];
    cst = c0l[(size_t)row * 1024 + tid];
    #pragma unroll
    for (int g = 0; g < 4; ++g) bv[g] = bsl[g * 512 + tid];
    hsh[tid] = f2h(h0l[(size_t)row * 1024 + tid]);
    __syncthreads();

    const uint4* Wq = (const uint4*)Wp2l;

    uint4 wc[16], wn[16];
    #pragma unroll
    for (int i = 0; i < 16; ++i) wc[i] = Wq[(size_t)i * 512 + tid];

    for (int t = 0; t < T_SEQ; ++t) {
        // gx loads issued early; consumed after the GEMM
        const u16* gp = gxbuf + ((size_t)t * BB + row) * G4;
        float gxv[4];
        #pragma unroll
        for (int g = 0; g < 4; ++g) gxv[g] = h2f(gp[(size_t)g * 512 + tid]);

        float acc[4] = {0.f, 0.f, 0.f, 0.f};

        #define COMPUTE_CHUNK(KCC, WREG)                                     \
        {                                                                    \
            u32 hr[16];                                                      \
            _Pragma("unroll")                                                \
            for (int q = 0; q < 4; ++q)                                      \
                *(uint4*)&hr[q * 4] =                                        \
                    *(const uint4*)&((const u32*)hsh)[(KCC) * 16 + q * 4];   \
            _Pragma("unroll")                                                \
            for (int g = 0; g < 4; ++g) {                                    \
                _Pragma("unroll")                                            \
                for (int j = 0; j < 4; ++j) {                                \
                    const uint4 w = WREG[g * 4 + j];                         \
                    acc[g] = dot2(hr[j*4+0], w.x, acc[g]);                   \
                    acc[g] = dot2(hr[j*4+1], w.y, acc[g]);                   \
                    acc[g] = dot2(hr[j*4+2], w.z, acc[g]);                   \
                    acc[g] = dot2(hr[j*4+3], w.w, acc[g]);                   \
                }                                                            \
            }                                                                \
        }

        #pragma unroll 1
        for (int kc = 0; kc < 16; kc += 2) {
            #pragma unroll
            for (int i = 0; i < 16; ++i)
                wn[i] = Wq[(size_t)((kc + 1) * 16 + i) * 512 + tid];
            COMPUTE_CHUNK(kc, wc)
            #pragma unroll
            for (int i = 0; i < 16; ++i)
                wc[i] = Wq[(size_t)((((kc + 2) & 15)) * 16 + i) * 512 + tid];
            COMPUTE_CHUNK(kc + 1, wn)
        }
        #undef COMPUTE_CHUNK

        // gates + block-local L1 norms
        float gv[4], pv[3];
        #pragma unroll
        for (int g = 0; g < 4; ++g) gv[g] = acc[g] + gxv[g] + bv[g];
        pv[0] = fabsf(gv[0]);
        pv[1] = fabsf(gv[1]);
        pv[2] = fabsf(gv[3]);
        #pragma unroll
        for (int d = 1; d < 64; d <<= 1)
            #pragma unroll
            for (int q = 0; q < 3; ++q) pv[q] += __shfl_xor(pv[q], d);
        const int wv = tid >> 6;
        if ((tid & 63) == 0) {
            #pragma unroll
            for (int q = 0; q < 3; ++q) red[wv][q] = pv[q];
        }
        __syncthreads();   // also: all GEMM reads of hsh are done past here
        float S[3];
        #pragma unroll
        for (int q = 0; q < 3; ++q) {
            float s = 0.f;
            #pragma unroll
            for (int w = 0; w < 8; ++w) s += red[w][q];
            S[q] = fmaxf(s, 1e-12f);
        }
        const float iv = 1.f / (1.f + expf(-gv[0] / S[0]));
        const float fv = 1.f / (1.f + expf(-gv[1] / S[1]));
        const float ov = 1.f / (1.f + expf(-gv[3] / S[2]));
        const float cn = fv * cst + iv * gv[2];
        cst = cn;
        const float hn = ov * fmaxf(cn, 0.f);
        Out[((size_t)row * T_SEQ + t) * 512 + tid] = hn;
        hsh[tid] = f2h(hn);
        __syncthreads();   // h(t) visible to next step's GEMM
    }
}

extern "C" void kernel_launch(void* const* d_in, const int* in_sizes, int n_in,
                              void* d_out, int out_size, void* d_ws, size_t ws_size,
                              hipStream_t stream)
{
    const float* x   = (const float*)d_in[0];
    const float* h0  = (const float*)d_in[1];
    const float* c0  = (const float*)d_in[2];
    const float* Wih = (const float*)d_in[3];
    const float* bih = (const float*)d_in[4];
    const float* Whh = (const float*)d_in[5];
    const float* bhh = (const float*)d_in[6];
    float* out = (float*)d_out;
    float* ws  = (float*)d_ws;

    // ws layout identical to R16/R17 (proven)
    float* part  = ws + 1024;                   // (unused)
    float* hbuf  = part + 16384;                // (unused)
    u32*   WpX   = (u32*)(hbuf + 65536);        // 1048576 u32 (2 layers)
    u32*   Wp2   = WpX + 1048576;               // 1048576 u32 (2 layers)
    float* bsum  = (float*)(Wp2 + 1048576);     // 4096 f
    u16*   gxbuf = (u16*)(bsum + 4096);         // 256 MB
    (void)ws_size;

    hipLaunchKernelGGL(pack_wx, dim3(512), dim3(256), 0, stream,
                       Wih, bih, bhh, WpX, bsum);
    hipLaunchKernelGGL(pack_wh2, dim3(1024), dim3(256), 0, stream,
                       Whh, Wp2);

    for (int l = 0; l < 2; ++l) {
        const float* Xin = (l == 0) ? x : (const float*)out;
        hipLaunchKernelGGL(prepass_gx, dim3(65536), dim3(256), 0, stream,
                           Xin, WpX + (size_t)l * 524288, gxbuf);
        hipLaunchKernelGGL(lstm_rec2, dim3(128), dim3(512), 0, stream,
                           gxbuf, Wp2 + (size_t)l * 524288,
                           bsum + l * 2048, c0 + l * 512, h0 + l * 512, out);
    }
}